// Round 9
// baseline (206.351 us; speedup 1.0000x reference)
//
#include <hip/hip_runtime.h>
#include <math.h>

#define NN 50
#define XS 12    // exchange-buffer row stride (floats), rows 16B-aligned
#define AWW 13   // A row words (u8-packed counts, 4 per u32, covers src 0..51)

__device__ __forceinline__ float rlane(float v, int k) {
    return __uint_as_float(__builtin_amdgcn_readlane(__float_as_uint(v), (unsigned)k));
}

// ---------------------------------------------------------------------------
// Kernel 1: emb_proj[r][0..9]=emb[r]@conv_w, [10..19]=emb[r]@cross_w.
// Block = 256 thr = 4 waves; wave w handles j-group w for rows blockIdx*64+lane.
// (w, j0) wave-uniform -> weight loads scalarize to s_load; rows L1-shared.
// Block 0 also transposes attn into attn_t.
// ---------------------------------------------------------------------------
__global__ __launch_bounds__(256) void precompute_proj(
    const float* __restrict__ emb,
    const float* __restrict__ conv_w,
    const float* __restrict__ cross_w,
    const float* __restrict__ attn,
    float* __restrict__ emb_proj,
    float* __restrict__ attn_t,
    int nrows)
{
    if (blockIdx.x == 0) {
        for (int i = threadIdx.x; i < NN * NN; i += 256) {
            int k = i / NN, r = i % NN;
            attn_t[k * NN + r] = attn[r * NN + k];
        }
    }
    const int lane = threadIdx.x & 63;
    const int w    = threadIdx.x >> 6;           // wave-uniform j-group
    const int r    = blockIdx.x * 64 + lane;
    if (r >= nrows) return;

    const float* wb = (w < 2) ? conv_w : cross_w;
    const int j0 = (w & 1) * 5;

    float acc[5] = {0.0f, 0.0f, 0.0f, 0.0f, 0.0f};
    const float4* rp = (const float4*)(emb + (size_t)r * 128);
#pragma unroll
    for (int q = 0; q < 32; ++q) {
        float4 v = rp[q];
        const float xs[4] = { v.x, v.y, v.z, v.w };
#pragma unroll
        for (int t = 0; t < 4; ++t) {
            const int k = 4 * q + t;
#pragma unroll
            for (int jj = 0; jj < 5; ++jj)
                acc[jj] += xs[t] * wb[k * 10 + j0 + jj];   // uniform -> s_load
        }
    }
    float* op = emb_proj + (size_t)r * 20 + w * 5;
#pragma unroll
    for (int jj = 0; jj < 5; ++jj) op[jj] = acc[jj];
}

// ---------------------------------------------------------------------------
// Kernel 2: fused forward. Block = 128 threads (2 waves), one sample/block.
// Wave g owns graph g. Matmuls via v_readlane broadcasts (VALU pipe), not LDS:
//   - self: xw'[k] lives in lane k's registers of the SAME wave.
//   - cross: wave g computes the OTHER graph's cross from its own ci regs;
//     only the 10-float result row crosses waves through LDS.
// LDS 10192 B -> 16 blocks/CU.
// ---------------------------------------------------------------------------
__global__ __launch_bounds__(128, 8) void gmn_fused(
    const int* __restrict__ tok_u_all, const int* __restrict__ tok_r_all,
    const int* __restrict__ adj_u_all, const int* __restrict__ adj_r_all,
    const float* __restrict__ emb_proj,
    const float* __restrict__ attn_t,
    const float* __restrict__ conv_b,
    const float* __restrict__ assign_w,
    const float* __restrict__ mp_w1, const float* __restrict__ mp_b1,
    const float* __restrict__ mp_w2, const float* __restrict__ mp_b2,
    const float* __restrict__ ffn_w1, const float* __restrict__ ffn_b1,
    const float* __restrict__ ffn_w2, const float* __restrict__ ffn_b2,
    float* __restrict__ out, int E)
{
    const int b    = blockIdx.x;
    const int tid  = threadIdx.x;
    const int lane = tid & 63;
    const int g    = tid >> 6;          // wave id == graph id

    __shared__ __attribute__((aligned(16))) unsigned s_A[2][NN * AWW];  // 5200 B
    __shared__ __attribute__((aligned(16))) float    s_x[2][NN * XS];   // 4800 B cross exchange
    __shared__ __attribute__((aligned(16))) float    s_g2[2][24];       // 192 B

    // ---- P1: zero own A; gather own rows into regs; build A (own-wave) ----
    for (int i = lane; i < NN * AWW; i += 64) s_A[g][i] = 0u;

    float rx[10], ci[10];
#pragma unroll
    for (int j = 0; j < 10; ++j) { rx[j] = 0.0f; ci[j] = 0.0f; }

    if (lane < NN) {
        const int t = (g ? tok_r_all : tok_u_all)[(size_t)b * NN + lane];
        const float4* p = (const float4*)(emb_proj + (size_t)t * 20);
        float4 v0 = p[0], v1 = p[1], v2 = p[2], v3 = p[3], v4 = p[4];
        rx[0] = v0.x; rx[1] = v0.y; rx[2] = v0.z; rx[3] = v0.w;
        rx[4] = v1.x; rx[5] = v1.y; rx[6] = v1.z; rx[7] = v1.w;
        rx[8] = v2.x; rx[9] = v2.y;
        ci[0] = v2.z; ci[1] = v2.w; ci[2] = v3.x; ci[3] = v3.y;
        ci[4] = v3.z; ci[5] = v3.w; ci[6] = v4.x; ci[7] = v4.y;
        ci[8] = v4.z; ci[9] = v4.w;
    }
    {
        const int* adj = (g ? adj_r_all : adj_u_all) + (size_t)b * 2 * E;
        for (int e = lane; e < E; e += 64) {
            int src = adj[e], dst = adj[E + e];
            atomicAdd(&s_A[g][dst * AWW + (src >> 2)], 1u << ((src & 3) * 8));
        }
    }
    // no barrier: s_A[g] is produced and consumed by wave g only (in-order DS)

    // ---- P2: A row -> VGPRs (bytesum -> di); scale rx ----------------------
    unsigned arow[AWW];
    const int rowbase = (lane < NN ? lane : 0) * AWW;
    unsigned ssum = 0;
#pragma unroll
    for (int kw = 0; kw < AWW; ++kw) {
        unsigned a = s_A[g][rowbase + kw];    // stride 13: conflict-free
        arow[kw] = a;
        ssum += (a & 0xFFu) + ((a >> 8) & 0xFFu) + ((a >> 16) & 0xFFu) + (a >> 24);
    }
    const float di = rsqrtf(1.0f + (float)ssum);
#pragma unroll
    for (int j = 0; j < 10; ++j) rx[j] *= di;     // xw' = dinv * xw

    // ---- P3: cross for the OTHER graph from own ci regs (readlane) --------
    if (lane < NN) {
        const int i = lane;
        float cr[10];
#pragma unroll
        for (int j = 0; j < 10; ++j) cr[j] = 0.0f;
#pragma unroll 5
        for (int k = 0; k < NN; ++k) {
            float aik = attn_t[k * NN + i];        // coalesced, L1-hot
#pragma unroll
            for (int j = 0; j < 10; ++j)
                cr[j] += aik * rlane(ci[j], k);    // SGPR broadcast, no LDS
        }
        float* cw = &s_x[g ^ 1][i * XS];           // result for OTHER graph
        *(float4*)(cw)     = make_float4(cr[0], cr[1], cr[2], cr[3]);
        *(float4*)(cw + 4) = make_float4(cr[4], cr[5], cr[6], cr[7]);
        *(float2*)(cw + 8) = make_float2(cr[8], cr[9]);
    }

    // ---- P4: self matmul via readlane (A from VGPRs, xw' from lane regs) --
    float sf[10];
    float h1[20];
    if (lane < NN) {
        float acc[10];
#pragma unroll
        for (int j = 0; j < 10; ++j) acc[j] = rx[j];   // identity term
#pragma unroll
        for (int kw = 0; kw < AWW; ++kw) {
            unsigned a = arow[kw];
#pragma unroll
            for (int t = 0; t < 4; ++t) {
                const int k = 4 * kw + t;
                if (k >= NN) break;                    // compile-time (unrolled)
                float c = (float)((a >> (8 * t)) & 0xFFu);
#pragma unroll
                for (int j = 0; j < 10; ++j)
                    acc[j] += c * rlane(rx[j], k);     // SGPR broadcast
            }
        }
#pragma unroll
        for (int j = 0; j < 10; ++j) sf[j] = di * acc[j] + conv_b[j];
    }
    __syncthreads();   // barrier 1: cross rows exchanged

    if (lane < NN) {
        const int i = lane;
        // own cross row from exchange buffer
        const float* cp = &s_x[g][i * XS];
        float4 c0 = *(const float4*)cp;
        float4 c1 = *(const float4*)(cp + 4);
        float2 c2 = *(const float2*)(cp + 8);
        const float cr[10] = { c0.x, c0.y, c0.z, c0.w,
                               c1.x, c1.y, c1.z, c1.w, c2.x, c2.y };

        // cosine distance
        float dot = 0.0f, na2 = 0.0f, nc2 = 0.0f;
        const float2* awp = (const float2*)(assign_w + i * 10);
#pragma unroll
        for (int q = 0; q < 5; ++q) {
            float2 wv = awp[q];
            float a0 = wv.x * sf[2 * q],     d0 = wv.x * cr[2 * q];
            float a1 = wv.y * sf[2 * q + 1], d1 = wv.y * cr[2 * q + 1];
            dot += a0 * d0 + a1 * d1;
            na2 += a0 * a0 + a1 * a1;
            nc2 += d0 * d0 + d1 * d1;
        }
        float dist = dot / (fmaxf(sqrtf(na2), 1e-8f) * fmaxf(sqrtf(nc2), 1e-8f));

        // h1 = relu([dist, self] @ w1 + b1)  (weights uniform -> SGPR operands)
#pragma unroll
        for (int o = 0; o < 20; ++o) {
            float t = mp_b1[o] + dist * mp_w1[o];
#pragma unroll
            for (int j = 0; j < 10; ++j) t += sf[j] * mp_w1[(1 + j) * 20 + o];
            h1[o] = fmaxf(t, 0.0f);
        }
    }

    // ---- h2[o] scalar + butterfly-max immediately (no h2 array) -----------
#pragma unroll
    for (int o = 0; o < 20; ++o) {
        float v = -INFINITY;
        if (lane < NN) {
            float t = mp_b2[o];
#pragma unroll
            for (int q = 0; q < 20; ++q) t += h1[q] * mp_w2[q * 20 + o];
            v = t;
        }
        v = fmaxf(v, __shfl_xor(v, 1));
        v = fmaxf(v, __shfl_xor(v, 2));
        v = fmaxf(v, __shfl_xor(v, 4));
        v = fmaxf(v, __shfl_xor(v, 8));
        v = fmaxf(v, __shfl_xor(v, 16));
        v = fmaxf(v, __shfl_xor(v, 32));
        if (lane == 0) s_g2[g][o] = v;
    }
    __syncthreads();   // barrier 2: publish s_g2

    // ---- P5: FFN on wave 0 ------------------------------------------------
    if (g == 0) {
        float p = 0.0f;
        if (lane < 40) {
            float acc = ffn_b1[lane];
#pragma unroll
            for (int i = 0; i < 20; ++i) {
                float gu = s_g2[0][i], gr = s_g2[1][i];
                acc += gu * ffn_w1[i * 40 + lane]
                     + gr * ffn_w1[(20 + i) * 40 + lane]
                     + gu * gr * ffn_w1[(40 + i) * 40 + lane]
                     + fabsf(gu - gr) * ffn_w1[(60 + i) * 40 + lane];
            }
            p = fmaxf(acc, 0.0f) * ffn_w2[lane];
        }
        p += __shfl_xor(p, 1);  p += __shfl_xor(p, 2);  p += __shfl_xor(p, 4);
        p += __shfl_xor(p, 8);  p += __shfl_xor(p, 16); p += __shfl_xor(p, 32);
        if (lane == 0)
            out[b] = 1.0f / (1.0f + expf(-(p + ffn_b2[0])));
    }
}

extern "C" void kernel_launch(void* const* d_in, const int* in_sizes, int n_in,
                              void* d_out, int out_size, void* d_ws, size_t ws_size,
                              hipStream_t stream)
{
    const int*   tok_u    = (const int*)d_in[0];
    const int*   tok_r    = (const int*)d_in[1];
    const int*   adj_u    = (const int*)d_in[2];
    const int*   adj_r    = (const int*)d_in[3];
    const float* emb      = (const float*)d_in[4];
    const float* conv_w   = (const float*)d_in[5];
    const float* conv_b   = (const float*)d_in[6];
    const float* cross_w  = (const float*)d_in[7];
    const float* attn     = (const float*)d_in[8];
    const float* assign_w = (const float*)d_in[9];
    const float* mp_w1    = (const float*)d_in[10];
    const float* mp_b1    = (const float*)d_in[11];
    const float* mp_w2    = (const float*)d_in[12];
    const float* mp_b2    = (const float*)d_in[13];
    const float* ffn_w1   = (const float*)d_in[14];
    const float* ffn_b1   = (const float*)d_in[15];
    const float* ffn_w2   = (const float*)d_in[16];
    const float* ffn_b2   = (const float*)d_in[17];

    const int B     = in_sizes[0] / 50;
    const int E     = in_sizes[2] / (2 * B);
    const int nrows = in_sizes[4] / 128;

    float* emb_proj = (float*)d_ws;                      // [nrows][20]
    float* attn_t   = emb_proj + (size_t)nrows * 20;     // [50][50] transposed

    precompute_proj<<<(nrows + 63) / 64, 256, 0, stream>>>(
        emb, conv_w, cross_w, attn, emb_proj, attn_t, nrows);

    gmn_fused<<<B, 128, 0, stream>>>(
        tok_u, tok_r, adj_u, adj_r, emb_proj, attn_t, conv_b,
        assign_w, mp_w1, mp_b1, mp_w2, mp_b2,
        ffn_w1, ffn_b1, ffn_w2, ffn_b2,
        (float*)d_out, E);
}

// Round 10
// 175.403 us; speedup vs baseline: 1.1764x; 1.1764x over previous
//
#include <hip/hip_runtime.h>
#include <math.h>

#define NN 50
#define XS 12    // s_buf row stride (floats), rows 16B-aligned
#define AWW 13   // A row words (u8-packed counts, 4 per u32, covers src 0..51)

// ---------------------------------------------------------------------------
// Kernel 1: emb_proj[r][0..9]=emb[r]@conv_w, [10..19]=emb[r]@cross_w.
// Block = 256 thr = 4 waves; wave w handles j-group w for rows blockIdx*64+lane.
// (w, j0) wave-uniform -> weight loads scalarize to s_load; rows L1-shared.
// Block 0 also transposes attn into attn_t.
// ---------------------------------------------------------------------------
__global__ __launch_bounds__(256) void precompute_proj(
    const float* __restrict__ emb,
    const float* __restrict__ conv_w,
    const float* __restrict__ cross_w,
    const float* __restrict__ attn,
    float* __restrict__ emb_proj,
    float* __restrict__ attn_t,
    int nrows)
{
    if (blockIdx.x == 0) {
        for (int i = threadIdx.x; i < NN * NN; i += 256) {
            int k = i / NN, r = i % NN;
            attn_t[k * NN + r] = attn[r * NN + k];
        }
    }
    const int lane = threadIdx.x & 63;
    const int w    = threadIdx.x >> 6;           // wave-uniform j-group
    const int r    = blockIdx.x * 64 + lane;
    if (r >= nrows) return;

    const float* wb = (w < 2) ? conv_w : cross_w;
    const int j0 = (w & 1) * 5;

    float acc[5] = {0.0f, 0.0f, 0.0f, 0.0f, 0.0f};
    const float4* rp = (const float4*)(emb + (size_t)r * 128);
#pragma unroll
    for (int q = 0; q < 32; ++q) {
        float4 v = rp[q];
        const float xs[4] = { v.x, v.y, v.z, v.w };
#pragma unroll
        for (int t = 0; t < 4; ++t) {
            const int k = 4 * q + t;
#pragma unroll
            for (int jj = 0; jj < 5; ++jj)
                acc[jj] += xs[t] * wb[k * 10 + j0 + jj];   // uniform -> s_load
        }
    }
    float* op = emb_proj + (size_t)r * 20 + w * 5;
#pragma unroll
    for (int jj = 0; jj < 5; ++jj) op[jj] = acc[jj];
}

// ---------------------------------------------------------------------------
// Kernel 2: fused forward. Block = 128 threads (2 waves), one sample/block.
// Wave g owns graph g. s_buf holds ci (cross-exchange) then xw' (own-wave).
// LDS 10192 B -> 16 blocks/CU. launch_bounds(128,4): loose VGPR cap so the
// allocator NEVER spills (spill traffic was the R7-R9 regression).
// ---------------------------------------------------------------------------
__global__ __launch_bounds__(128, 4) void gmn_fused(
    const int* __restrict__ tok_u_all, const int* __restrict__ tok_r_all,
    const int* __restrict__ adj_u_all, const int* __restrict__ adj_r_all,
    const float* __restrict__ emb_proj,
    const float* __restrict__ attn_t,
    const float* __restrict__ conv_b,
    const float* __restrict__ assign_w,
    const float* __restrict__ mp_w1, const float* __restrict__ mp_b1,
    const float* __restrict__ mp_w2, const float* __restrict__ mp_b2,
    const float* __restrict__ ffn_w1, const float* __restrict__ ffn_b1,
    const float* __restrict__ ffn_w2, const float* __restrict__ ffn_b2,
    float* __restrict__ out, int E)
{
    const int b    = blockIdx.x;
    const int tid  = threadIdx.x;
    const int lane = tid & 63;
    const int g    = tid >> 6;          // wave id == graph id

    __shared__ __attribute__((aligned(16))) unsigned s_A[2][NN * AWW];  // 5200 B
    __shared__ __attribute__((aligned(16))) float    s_buf[2][NN * XS]; // 4800 B: ci, then xw'
    __shared__ __attribute__((aligned(16))) float    s_g2[2][24];       // 192 B

    // ---- P1: zero A; gather own rows (rx + ci into s_buf); build A --------
    for (int i = lane; i < NN * AWW; i += 64) s_A[g][i] = 0u;

    float rx[10];
#pragma unroll
    for (int j = 0; j < 10; ++j) rx[j] = 0.0f;

    if (lane < NN) {
        const int t = (g ? tok_r_all : tok_u_all)[(size_t)b * NN + lane];
        const float4* p = (const float4*)(emb_proj + (size_t)t * 20);
        float4 v0 = p[0], v1 = p[1], v2 = p[2], v3 = p[3], v4 = p[4];
        rx[0] = v0.x; rx[1] = v0.y; rx[2] = v0.z; rx[3] = v0.w;
        rx[4] = v1.x; rx[5] = v1.y; rx[6] = v1.z; rx[7] = v1.w;
        rx[8] = v2.x; rx[9] = v2.y;
        float* ci = &s_buf[g][lane * XS];
        *(float4*)(ci)     = make_float4(v2.z, v2.w, v3.x, v3.y);
        *(float4*)(ci + 4) = make_float4(v3.z, v3.w, v4.x, v4.y);
        *(float2*)(ci + 8) = make_float2(v4.z, v4.w);
    }
    {
        const int* adj = (g ? adj_r_all : adj_u_all) + (size_t)b * 2 * E;
        for (int e = lane; e < E; e += 64) {
            int src = adj[e], dst = adj[E + e];
            atomicAdd(&s_A[g][dst * AWW + (src >> 2)], 1u << ((src & 3) * 8));
        }
    }
    __syncthreads();   // barrier 1: publishes ci across waves

    // ---- P2: A row -> VGPRs (bytesum -> di); scale rx; cross matmul -------
    unsigned arow[AWW];
    const int rowbase = (lane < NN ? lane : 0) * AWW;
    unsigned ssum = 0;
#pragma unroll
    for (int kw = 0; kw < AWW; ++kw) {
        unsigned a = s_A[g][rowbase + kw];    // stride 13: conflict-free
        arow[kw] = a;
        ssum += (a & 0xFFu) + ((a >> 8) & 0xFFu) + ((a >> 16) & 0xFFu) + (a >> 24);
    }
    const float di = rsqrtf(1.0f + (float)ssum);
#pragma unroll
    for (int j = 0; j < 10; ++j) rx[j] *= di;     // xw' = dinv * xw

    float cr[10];
#pragma unroll
    for (int j = 0; j < 10; ++j) cr[j] = 0.0f;

    if (lane < NN) {
        // cross[i][:] = sum_k attn[i][k] * ci_other[k][:]
        const int i = lane;
        const float* cio = s_buf[g ^ 1];
#pragma unroll 10
        for (int k = 0; k < NN; ++k) {
            float aik = attn_t[k * NN + i];            // coalesced, L1-hot
            const float* crow = &cio[k * XS];
            float4 c0 = *(const float4*)crow;          // uniform broadcast LDS
            float4 c1 = *(const float4*)(crow + 4);
            float2 c2 = *(const float2*)(crow + 8);
            cr[0] += aik * c0.x; cr[1] += aik * c0.y;
            cr[2] += aik * c0.z; cr[3] += aik * c0.w;
            cr[4] += aik * c1.x; cr[5] += aik * c1.y;
            cr[6] += aik * c1.z; cr[7] += aik * c1.w;
            cr[8] += aik * c2.x; cr[9] += aik * c2.y;
        }
    }
    __syncthreads();   // barrier 2: cross reads of ci done -> buf reusable

    // ---- P3: publish xw' (own-wave); self matmul; cosine; MLP -------------
    if (lane < NN) {
        float* x = &s_buf[g][lane * XS];
        *(float4*)(x)     = make_float4(rx[0], rx[1], rx[2], rx[3]);
        *(float4*)(x + 4) = make_float4(rx[4], rx[5], rx[6], rx[7]);
        *(float2*)(x + 8) = make_float2(rx[8], rx[9]);
    }
    __builtin_amdgcn_wave_barrier();   // keep write->read order (own wave)

    float sf[10];
    float h1[20];

    if (lane < NN) {
        float acc[10];
#pragma unroll
        for (int j = 0; j < 10; ++j) acc[j] = rx[j];   // identity term
#pragma unroll
        for (int kw = 0; kw < 12; ++kw) {              // rows 0..47
            unsigned a = arow[kw];
            float cc[4] = { (float)(a & 0xFFu), (float)((a >> 8) & 0xFFu),
                            (float)((a >> 16) & 0xFFu), (float)(a >> 24) };
            const float* x0 = &s_buf[g][(4 * kw) * XS];
#pragma unroll
            for (int t = 0; t < 4; ++t) {
                const float c = cc[t];
                const float* xr = x0 + t * XS;         // uniform broadcast LDS
                float4 p0 = *(const float4*)xr;
                float4 p1 = *(const float4*)(xr + 4);
                float2 p2 = *(const float2*)(xr + 8);
                acc[0] += c * p0.x; acc[1] += c * p0.y;
                acc[2] += c * p0.z; acc[3] += c * p0.w;
                acc[4] += c * p1.x; acc[5] += c * p1.y;
                acc[6] += c * p1.z; acc[7] += c * p1.w;
                acc[8] += c * p2.x; acc[9] += c * p2.y;
            }
        }
        {   // kw = 12: rows 48,49 only
            unsigned a = arow[12];
            float cc[2] = { (float)(a & 0xFFu), (float)((a >> 8) & 0xFFu) };
            const float* x0 = &s_buf[g][48 * XS];
#pragma unroll
            for (int t = 0; t < 2; ++t) {
                const float c = cc[t];
                const float* xr = x0 + t * XS;
                float4 p0 = *(const float4*)xr;
                float4 p1 = *(const float4*)(xr + 4);
                float2 p2 = *(const float2*)(xr + 8);
                acc[0] += c * p0.x; acc[1] += c * p0.y;
                acc[2] += c * p0.z; acc[3] += c * p0.w;
                acc[4] += c * p1.x; acc[5] += c * p1.y;
                acc[6] += c * p1.z; acc[7] += c * p1.w;
                acc[8] += c * p2.x; acc[9] += c * p2.y;
            }
        }
#pragma unroll
        for (int j = 0; j < 10; ++j) sf[j] = di * acc[j] + conv_b[j];

        // cosine distance
        float dot = 0.0f, na2 = 0.0f, nc2 = 0.0f;
        const float2* awp = (const float2*)(assign_w + lane * 10);
#pragma unroll
        for (int q = 0; q < 5; ++q) {
            float2 wv = awp[q];
            float a0 = wv.x * sf[2 * q],     d0 = wv.x * cr[2 * q];
            float a1 = wv.y * sf[2 * q + 1], d1 = wv.y * cr[2 * q + 1];
            dot += a0 * d0 + a1 * d1;
            na2 += a0 * a0 + a1 * a1;
            nc2 += d0 * d0 + d1 * d1;
        }
        float dist = dot / (fmaxf(sqrtf(na2), 1e-8f) * fmaxf(sqrtf(nc2), 1e-8f));

        // h1 = relu([dist, self] @ w1 + b1)  (weights uniform -> SGPR operands)
#pragma unroll
        for (int o = 0; o < 20; ++o) {
            float t = mp_b1[o] + dist * mp_w1[o];
#pragma unroll
            for (int j = 0; j < 10; ++j) t += sf[j] * mp_w1[(1 + j) * 20 + o];
            h1[o] = fmaxf(t, 0.0f);
        }
    }

    // ---- h2[o] scalar + butterfly-max immediately (no h2 array) -----------
#pragma unroll
    for (int o = 0; o < 20; ++o) {
        float v = -INFINITY;
        if (lane < NN) {
            float t = mp_b2[o];
#pragma unroll
            for (int q = 0; q < 20; ++q) t += h1[q] * mp_w2[q * 20 + o];
            v = t;
        }
        v = fmaxf(v, __shfl_xor(v, 1));
        v = fmaxf(v, __shfl_xor(v, 2));
        v = fmaxf(v, __shfl_xor(v, 4));
        v = fmaxf(v, __shfl_xor(v, 8));
        v = fmaxf(v, __shfl_xor(v, 16));
        v = fmaxf(v, __shfl_xor(v, 32));
        if (lane == 0) s_g2[g][o] = v;
    }
    __syncthreads();   // barrier 3: publish s_g2

    // ---- P4: FFN on wave 0 ------------------------------------------------
    if (g == 0) {
        float p = 0.0f;
        if (lane < 40) {
            float acc = ffn_b1[lane];
#pragma unroll
            for (int i = 0; i < 20; ++i) {
                float gu = s_g2[0][i], gr = s_g2[1][i];
                acc += gu * ffn_w1[i * 40 + lane]
                     + gr * ffn_w1[(20 + i) * 40 + lane]
                     + gu * gr * ffn_w1[(40 + i) * 40 + lane]
                     + fabsf(gu - gr) * ffn_w1[(60 + i) * 40 + lane];
            }
            p = fmaxf(acc, 0.0f) * ffn_w2[lane];
        }
        p += __shfl_xor(p, 1);  p += __shfl_xor(p, 2);  p += __shfl_xor(p, 4);
        p += __shfl_xor(p, 8);  p += __shfl_xor(p, 16); p += __shfl_xor(p, 32);
        if (lane == 0)
            out[b] = 1.0f / (1.0f + expf(-(p + ffn_b2[0])));
    }
}

extern "C" void kernel_launch(void* const* d_in, const int* in_sizes, int n_in,
                              void* d_out, int out_size, void* d_ws, size_t ws_size,
                              hipStream_t stream)
{
    const int*   tok_u    = (const int*)d_in[0];
    const int*   tok_r    = (const int*)d_in[1];
    const int*   adj_u    = (const int*)d_in[2];
    const int*   adj_r    = (const int*)d_in[3];
    const float* emb      = (const float*)d_in[4];
    const float* conv_w   = (const float*)d_in[5];
    const float* conv_b   = (const float*)d_in[6];
    const float* cross_w  = (const float*)d_in[7];
    const float* attn     = (const float*)d_in[8];
    const float* assign_w = (const float*)d_in[9];
    const float* mp_w1    = (const float*)d_in[10];
    const float* mp_b1    = (const float*)d_in[11];
    const float* mp_w2    = (const float*)d_in[12];
    const float* mp_b2    = (const float*)d_in[13];
    const float* ffn_w1   = (const float*)d_in[14];
    const float* ffn_b1   = (const float*)d_in[15];
    const float* ffn_w2   = (const float*)d_in[16];
    const float* ffn_b2   = (const float*)d_in[17];

    const int B     = in_sizes[0] / 50;
    const int E     = in_sizes[2] / (2 * B);
    const int nrows = in_sizes[4] / 128;

    float* emb_proj = (float*)d_ws;                      // [nrows][20]
    float* attn_t   = emb_proj + (size_t)nrows * 20;     // [50][50] transposed

    precompute_proj<<<(nrows + 63) / 64, 256, 0, stream>>>(
        emb, conv_w, cross_w, attn, emb_proj, attn_t, nrows);

    gmn_fused<<<B, 128, 0, stream>>>(
        tok_u, tok_r, adj_u, adj_r, emb_proj, attn_t, conv_b,
        assign_w, mp_w1, mp_b1, mp_w2, mp_b2,
        ffn_w1, ffn_b1, ffn_w2, ffn_b2,
        (float*)d_out, E);
}

// Round 12
// 171.372 us; speedup vs baseline: 1.2041x; 1.0235x over previous
//
#include <hip/hip_runtime.h>
#include <math.h>

#define NN 50
#define XS 12    // s_buf row stride (floats), rows 16B-aligned
#define AWW 13   // A row words (u8-packed counts, 4 per u32, covers src 0..51)
#define APAD 652 // per-graph A block words (16B-aligned, >= NN*AWW=650)

// ---------------------------------------------------------------------------
// Kernel 1: emb_proj[r][0..9]=emb[r]@conv_w, [10..19]=emb[r]@cross_w.
// Block = 256 thr = 4 waves; wave w handles j-group w for rows blockIdx*64+lane.
// (w, j0) wave-uniform -> weight loads scalarize to s_load; rows L1-shared.
// Block 0 also transposes attn into attn_t.
// ---------------------------------------------------------------------------
__global__ __launch_bounds__(256) void precompute_proj(
    const float* __restrict__ emb,
    const float* __restrict__ conv_w,
    const float* __restrict__ cross_w,
    const float* __restrict__ attn,
    float* __restrict__ emb_proj,
    float* __restrict__ attn_t,
    int nrows)
{
    if (blockIdx.x == 0) {
        for (int i = threadIdx.x; i < NN * NN; i += 256) {
            int k = i / NN, r = i % NN;
            attn_t[k * NN + r] = attn[r * NN + k];
        }
    }
    const int lane = threadIdx.x & 63;
    const int w    = threadIdx.x >> 6;           // wave-uniform j-group
    const int r    = blockIdx.x * 64 + lane;
    if (r >= nrows) return;

    const float* wb = (w < 2) ? conv_w : cross_w;
    const int j0 = (w & 1) * 5;

    float acc[5] = {0.0f, 0.0f, 0.0f, 0.0f, 0.0f};
    const float4* rp = (const float4*)(emb + (size_t)r * 128);
#pragma unroll
    for (int q = 0; q < 32; ++q) {
        float4 v = rp[q];
        const float xs[4] = { v.x, v.y, v.z, v.w };
#pragma unroll
        for (int t = 0; t < 4; ++t) {
            const int k = 4 * q + t;
#pragma unroll
            for (int jj = 0; jj < 5; ++jj)
                acc[jj] += xs[t] * wb[k * 10 + j0 + jj];   // uniform -> s_load
        }
    }
    float* op = emb_proj + (size_t)r * 20 + w * 5;
#pragma unroll
    for (int jj = 0; jj < 5; ++jj) op[jj] = acc[jj];
}

// ---------------------------------------------------------------------------
// Kernel 2: fused forward. Block = 128 threads (2 waves), one sample/block.
// Wave g owns graph g. s_buf holds ci (cross-exchange) then xw' (own-wave).
// LDS 10208 B -> 16 blocks/CU. No arow register cache (A re-read from LDS):
// natural VGPR demand < 64 so 8 waves/SIMD are possible WITHOUT spills.
// ---------------------------------------------------------------------------
__global__ __launch_bounds__(128, 4) void gmn_fused(
    const int* __restrict__ tok_u_all, const int* __restrict__ tok_r_all,
    const int* __restrict__ adj_u_all, const int* __restrict__ adj_r_all,
    const float* __restrict__ emb_proj,
    const float* __restrict__ attn_t,
    const float* __restrict__ conv_b,
    const float* __restrict__ assign_w,
    const float* __restrict__ mp_w1, const float* __restrict__ mp_b1,
    const float* __restrict__ mp_w2, const float* __restrict__ mp_b2,
    const float* __restrict__ ffn_w1, const float* __restrict__ ffn_b1,
    const float* __restrict__ ffn_w2, const float* __restrict__ ffn_b2,
    float* __restrict__ out, int E)
{
    const int b    = blockIdx.x;
    const int tid  = threadIdx.x;
    const int lane = tid & 63;
    const int g    = tid >> 6;          // wave id == graph id

    __shared__ __attribute__((aligned(16))) unsigned s_A[2][APAD];      // 5216 B
    __shared__ __attribute__((aligned(16))) float    s_buf[2][NN * XS]; // 4800 B: ci, then xw'
    __shared__ __attribute__((aligned(16))) float    s_g2[2][24];       // 192 B

    // ---- P1: zero A (uint4); gather own rows (rx + ci); build A -----------
    {
        uint4 z4 = make_uint4(0u, 0u, 0u, 0u);
        uint4* az = (uint4*)s_A[g];
        for (int i = lane; i < APAD / 4; i += 64) az[i] = z4;
    }

    float rx[10];
#pragma unroll
    for (int j = 0; j < 10; ++j) rx[j] = 0.0f;

    if (lane < NN) {
        const int t = (g ? tok_r_all : tok_u_all)[(size_t)b * NN + lane];
        const float4* p = (const float4*)(emb_proj + (size_t)t * 20);
        float4 v0 = p[0], v1 = p[1], v2 = p[2], v3 = p[3], v4 = p[4];
        rx[0] = v0.x; rx[1] = v0.y; rx[2] = v0.z; rx[3] = v0.w;
        rx[4] = v1.x; rx[5] = v1.y; rx[6] = v1.z; rx[7] = v1.w;
        rx[8] = v2.x; rx[9] = v2.y;
        float* ci = &s_buf[g][lane * XS];
        *(float4*)(ci)     = make_float4(v2.z, v2.w, v3.x, v3.y);
        *(float4*)(ci + 4) = make_float4(v3.z, v3.w, v4.x, v4.y);
        *(float2*)(ci + 8) = make_float2(v4.z, v4.w);
    }
    {
        const int* adj = (g ? adj_r_all : adj_u_all) + (size_t)b * 2 * E;
        if ((E & 3) == 0) {
            const int4* s4 = (const int4*)adj;         // srcs
            const int4* d4 = (const int4*)(adj + E);   // dsts
            for (int e4 = lane; e4 < E / 4; e4 += 64) {
                int4 sv = s4[e4], dv = d4[e4];
                atomicAdd(&s_A[g][dv.x * AWW + (sv.x >> 2)], 1u << ((sv.x & 3) * 8));
                atomicAdd(&s_A[g][dv.y * AWW + (sv.y >> 2)], 1u << ((sv.y & 3) * 8));
                atomicAdd(&s_A[g][dv.z * AWW + (sv.z >> 2)], 1u << ((sv.z & 3) * 8));
                atomicAdd(&s_A[g][dv.w * AWW + (sv.w >> 2)], 1u << ((sv.w & 3) * 8));
            }
        } else {
            for (int e = lane; e < E; e += 64) {
                int src = adj[e], dst = adj[E + e];
                atomicAdd(&s_A[g][dst * AWW + (src >> 2)], 1u << ((src & 3) * 8));
            }
        }
    }
    __syncthreads();   // barrier 1: publishes ci across waves

    // ---- P2: deg from A-row bytesum; scale rx; cross matmul ---------------
    const int rowbase = (lane < NN ? lane : 0) * AWW;
    unsigned ssum = 0;
#pragma unroll
    for (int kw = 0; kw < AWW; ++kw) {
        unsigned a = s_A[g][rowbase + kw];    // stride 13: conflict-free
        ssum += (a & 0xFFu) + ((a >> 8) & 0xFFu) + ((a >> 16) & 0xFFu) + (a >> 24);
    }
    const float di = rsqrtf(1.0f + (float)ssum);
#pragma unroll
    for (int j = 0; j < 10; ++j) rx[j] *= di;     // xw' = dinv * xw

    float cr[10];
#pragma unroll
    for (int j = 0; j < 10; ++j) cr[j] = 0.0f;

    if (lane < NN) {
        // cross[i][:] = sum_k attn[i][k] * ci_other[k][:]
        const int i = lane;
        const float* cio = s_buf[g ^ 1];
#pragma unroll 10
        for (int k = 0; k < NN; ++k) {
            float aik = attn_t[k * NN + i];            // coalesced, L1-hot
            const float* crow = &cio[k * XS];
            float4 c0 = *(const float4*)crow;          // uniform broadcast LDS
            float4 c1 = *(const float4*)(crow + 4);
            float2 c2 = *(const float2*)(crow + 8);
            cr[0] += aik * c0.x; cr[1] += aik * c0.y;
            cr[2] += aik * c0.z; cr[3] += aik * c0.w;
            cr[4] += aik * c1.x; cr[5] += aik * c1.y;
            cr[6] += aik * c1.z; cr[7] += aik * c1.w;
            cr[8] += aik * c2.x; cr[9] += aik * c2.y;
        }
    }
    __syncthreads();   // barrier 2: cross reads of ci done -> buf reusable

    // ---- P3: publish xw' (own-wave); self matmul (A re-read); MLP ---------
    if (lane < NN) {
        float* x = &s_buf[g][lane * XS];
        *(float4*)(x)     = make_float4(rx[0], rx[1], rx[2], rx[3]);
        *(float4*)(x + 4) = make_float4(rx[4], rx[5], rx[6], rx[7]);
        *(float2*)(x + 8) = make_float2(rx[8], rx[9]);
    }
    __builtin_amdgcn_wave_barrier();   // keep write->read order (own wave)

    float sf[10];
    float h1[20];

    if (lane < NN) {
        float acc[10];
#pragma unroll
        for (int j = 0; j < 10; ++j) acc[j] = rx[j];   // identity term
#pragma unroll
        for (int kw = 0; kw < 12; ++kw) {              // rows 0..47
            unsigned a = s_A[g][lane * AWW + kw];      // re-read: conflict-free
            float cc[4] = { (float)(a & 0xFFu), (float)((a >> 8) & 0xFFu),
                            (float)((a >> 16) & 0xFFu), (float)(a >> 24) };
            const float* x0 = &s_buf[g][(4 * kw) * XS];
#pragma unroll
            for (int t = 0; t < 4; ++t) {
                const float c = cc[t];
                const float* xr = x0 + t * XS;         // uniform broadcast LDS
                float4 p0 = *(const float4*)xr;
                float4 p1 = *(const float4*)(xr + 4);
                float2 p2 = *(const float2*)(xr + 8);
                acc[0] += c * p0.x; acc[1] += c * p0.y;
                acc[2] += c * p0.z; acc[3] += c * p0.w;
                acc[4] += c * p1.x; acc[5] += c * p1.y;
                acc[6] += c * p1.z; acc[7] += c * p1.w;
                acc[8] += c * p2.x; acc[9] += c * p2.y;
            }
        }
        {   // kw = 12: rows 48,49 only
            unsigned a = s_A[g][lane * AWW + 12];
            float cc[2] = { (float)(a & 0xFFu), (float)((a >> 8) & 0xFFu) };
            const float* x0 = &s_buf[g][48 * XS];
#pragma unroll
            for (int t = 0; t < 2; ++t) {
                const float c = cc[t];
                const float* xr = x0 + t * XS;
                float4 p0 = *(const float4*)xr;
                float4 p1 = *(const float4*)(xr + 4);
                float2 p2 = *(const float2*)(xr + 8);
                acc[0] += c * p0.x; acc[1] += c * p0.y;
                acc[2] += c * p0.z; acc[3] += c * p0.w;
                acc[4] += c * p1.x; acc[5] += c * p1.y;
                acc[6] += c * p1.z; acc[7] += c * p1.w;
                acc[8] += c * p2.x; acc[9] += c * p2.y;
            }
        }
#pragma unroll
        for (int j = 0; j < 10; ++j) sf[j] = di * acc[j] + conv_b[j];

        // cosine distance
        float dot = 0.0f, na2 = 0.0f, nc2 = 0.0f;
        const float2* awp = (const float2*)(assign_w + lane * 10);
#pragma unroll
        for (int q = 0; q < 5; ++q) {
            float2 wv = awp[q];
            float a0 = wv.x * sf[2 * q],     d0 = wv.x * cr[2 * q];
            float a1 = wv.y * sf[2 * q + 1], d1 = wv.y * cr[2 * q + 1];
            dot += a0 * d0 + a1 * d1;
            na2 += a0 * a0 + a1 * a1;
            nc2 += d0 * d0 + d1 * d1;
        }
        float dist = dot / (fmaxf(sqrtf(na2), 1e-8f) * fmaxf(sqrtf(nc2), 1e-8f));

        // h1 = relu([dist, self] @ w1 + b1)  (weights uniform -> SGPR operands)
#pragma unroll
        for (int o = 0; o < 20; ++o) {
            float t = mp_b1[o] + dist * mp_w1[o];
#pragma unroll
            for (int j = 0; j < 10; ++j) t += sf[j] * mp_w1[(1 + j) * 20 + o];
            h1[o] = fmaxf(t, 0.0f);
        }
    }

    // ---- h2[o] scalar + butterfly-max immediately (no h2 array) -----------
#pragma unroll
    for (int o = 0; o < 20; ++o) {
        float v = -INFINITY;
        if (lane < NN) {
            float t = mp_b2[o];
#pragma unroll
            for (int q = 0; q < 20; ++q) t += h1[q] * mp_w2[q * 20 + o];
            v = t;
        }
        v = fmaxf(v, __shfl_xor(v, 1));
        v = fmaxf(v, __shfl_xor(v, 2));
        v = fmaxf(v, __shfl_xor(v, 4));
        v = fmaxf(v, __shfl_xor(v, 8));
        v = fmaxf(v, __shfl_xor(v, 16));
        v = fmaxf(v, __shfl_xor(v, 32));
        if (lane == 0) s_g2[g][o] = v;
    }
    __syncthreads();   // barrier 3: publish s_g2

    // ---- P4: FFN on wave 0 ------------------------------------------------
    if (g == 0) {
        float p = 0.0f;
        if (lane < 40) {
            float acc = ffn_b1[lane];
#pragma unroll
            for (int i = 0; i < 20; ++i) {
                float gu = s_g2[0][i], gr = s_g2[1][i];
                acc += gu * ffn_w1[i * 40 + lane]
                     + gr * ffn_w1[(20 + i) * 40 + lane]
                     + gu * gr * ffn_w1[(40 + i) * 40 + lane]
                     + fabsf(gu - gr) * ffn_w1[(60 + i) * 40 + lane];
            }
            p = fmaxf(acc, 0.0f) * ffn_w2[lane];
        }
        p += __shfl_xor(p, 1);  p += __shfl_xor(p, 2);  p += __shfl_xor(p, 4);
        p += __shfl_xor(p, 8);  p += __shfl_xor(p, 16); p += __shfl_xor(p, 32);
        if (lane == 0)
            out[b] = 1.0f / (1.0f + expf(-(p + ffn_b2[0])));
    }
}

extern "C" void kernel_launch(void* const* d_in, const int* in_sizes, int n_in,
                              void* d_out, int out_size, void* d_ws, size_t ws_size,
                              hipStream_t stream)
{
    const int*   tok_u    = (const int*)d_in[0];
    const int*   tok_r    = (const int*)d_in[1];
    const int*   adj_u    = (const int*)d_in[2];
    const int*   adj_r    = (const int*)d_in[3];
    const float* emb      = (const float*)d_in[4];
    const float* conv_w   = (const float*)d_in[5];
    const float* conv_b   = (const float*)d_in[6];
    const float* cross_w  = (const float*)d_in[7];
    const float* attn     = (const float*)d_in[8];
    const float* assign_w = (const float*)d_in[9];
    const float* mp_w1    = (const float*)d_in[10];
    const float* mp_b1    = (const float*)d_in[11];
    const float* mp_w2    = (const float*)d_in[12];
    const float* mp_b2    = (const float*)d_in[13];
    const float* ffn_w1   = (const float*)d_in[14];
    const float* ffn_b1   = (const float*)d_in[15];
    const float* ffn_w2   = (const float*)d_in[16];
    const float* ffn_b2   = (const float*)d_in[17];

    const int B     = in_sizes[0] / 50;
    const int E     = in_sizes[2] / (2 * B);
    const int nrows = in_sizes[4] / 128;

    float* emb_proj = (float*)d_ws;                      // [nrows][20]
    float* attn_t   = emb_proj + (size_t)nrows * 20;     // [50][50] transposed

    precompute_proj<<<(nrows + 63) / 64, 256, 0, stream>>>(
        emb, conv_w, cross_w, attn, emb_proj, attn_t, nrows);

    gmn_fused<<<B, 128, 0, stream>>>(
        tok_u, tok_r, adj_u, adj_r, emb_proj, attn_t, conv_b,
        assign_w, mp_w1, mp_b1, mp_w2, mp_b2,
        ffn_w1, ffn_b1, ffn_w2, ffn_b2,
        (float*)d_out, E);
}